// Round 1
// baseline (1618.244 us; speedup 1.0000x reference)
//
#include <hip/hip_runtime.h>

typedef _Float16 f16;
typedef _Float16 f16x2 __attribute__((ext_vector_type(2)));
typedef _Float16 f16x4 __attribute__((ext_vector_type(4)));
typedef _Float16 f16x8 __attribute__((ext_vector_type(8)));
typedef float    f32x4 __attribute__((ext_vector_type(4)));

static __device__ __forceinline__ float dot4(uint4 w, uint4 h, float acc) {
    acc = __builtin_amdgcn_fdot2(__builtin_bit_cast(f16x2, w.x), __builtin_bit_cast(f16x2, h.x), acc, false);
    acc = __builtin_amdgcn_fdot2(__builtin_bit_cast(f16x2, w.y), __builtin_bit_cast(f16x2, h.y), acc, false);
    acc = __builtin_amdgcn_fdot2(__builtin_bit_cast(f16x2, w.z), __builtin_bit_cast(f16x2, h.z), acc, false);
    acc = __builtin_amdgcn_fdot2(__builtin_bit_cast(f16x2, w.w), __builtin_bit_cast(f16x2, h.w), acc, false);
    return acc;
}

// ---------------- Phase 0: convert W_ih, W_hh to f16 ----------------
__global__ __launch_bounds__(256) void cvt_w(const float4* __restrict__ wih4,
                                             const float4* __restrict__ whh4,
                                             f16x4* __restrict__ wih16,
                                             f16x4* __restrict__ whh16) {
    int idx = blockIdx.x * 256 + threadIdx.x;   // 98304 total float4s
    if (idx < 32768) {
        float4 v = wih4[idx];
        wih16[idx] = (f16x4){(f16)v.x, (f16)v.y, (f16)v.z, (f16)v.w};
    } else if (idx < 98304) {
        int k = idx - 32768;
        float4 v = whh4[k];
        whh16[k] = (f16x4){(f16)v.x, (f16)v.y, (f16)v.z, (f16)v.w};
    }
}

// ---------------- Phase 1: xp = x @ W_ih^T + (b_ih + b_hh), f16 out ----------------
// grid = (tc, 4), block = 256. Tile 128x128, K=256 in 8 steps of 32.
__global__ __launch_bounds__(256) void gemm_xp(const float* __restrict__ x,
                                               const f16* __restrict__ wih,
                                               const float* __restrict__ bih,
                                               const float* __restrict__ bhh,
                                               f16* __restrict__ xp,
                                               int tc, int t0, int L) {
    __shared__ f16 As[128][48];   // +16 pad: stride 96B -> ~2-way conflicts max
    __shared__ f16 Bs[128][48];
    int tid = threadIdx.x;
    int r = tid >> 1, kh = (tid & 1) * 16;

    long mbase = (long)blockIdx.x * 128;
    int jb = blockIdx.y * 128;
    long mp = mbase + r;
    int n = (int)(mp / tc);
    int trel = (int)(mp - (long)n * tc);
    const float* xrow = x + ((long)n * L + t0 + trel) * 256 + kh;
    const f16* wrow = wih + (jb + r) * 256 + kh;

    int w = tid >> 6, l = tid & 63, lr = l & 15, lk = l >> 4;
    int wm = w & 1, wn = w >> 1;

    f32x4 acc[4][4] = {};

    for (int kk = 0; kk < 256; kk += 32) {
        // global loads issued before the barrier (prefetch across previous compute)
        float4 a0 = *(const float4*)(xrow + kk);
        float4 a1 = *(const float4*)(xrow + kk + 4);
        float4 a2 = *(const float4*)(xrow + kk + 8);
        float4 a3 = *(const float4*)(xrow + kk + 12);
        uint4  b0 = *(const uint4*)(wrow + kk);
        uint4  b1 = *(const uint4*)(wrow + kk + 8);
        f16x8 ca = {(f16)a0.x,(f16)a0.y,(f16)a0.z,(f16)a0.w,(f16)a1.x,(f16)a1.y,(f16)a1.z,(f16)a1.w};
        f16x8 cb = {(f16)a2.x,(f16)a2.y,(f16)a2.z,(f16)a2.w,(f16)a3.x,(f16)a3.y,(f16)a3.z,(f16)a3.w};
        __syncthreads();   // previous compute done before overwrite (no-op cost on first iter)
        *(f16x8*)&As[r][kh]     = ca;
        *(f16x8*)&As[r][kh + 8] = cb;
        *(uint4*)&Bs[r][kh]     = b0;
        *(uint4*)&Bs[r][kh + 8] = b1;
        __syncthreads();

        uint4 af[4], bf[4];
#pragma unroll
        for (int mi = 0; mi < 4; ++mi) af[mi] = *(const uint4*)&As[wm * 64 + mi * 16 + lr][lk * 8];
#pragma unroll
        for (int ni = 0; ni < 4; ++ni) bf[ni] = *(const uint4*)&Bs[wn * 64 + ni * 16 + lr][lk * 8];
#pragma unroll
        for (int mi = 0; mi < 4; ++mi)
#pragma unroll
            for (int ni = 0; ni < 4; ++ni)
                acc[mi][ni] = __builtin_amdgcn_mfma_f32_16x16x32_f16(
                    __builtin_bit_cast(f16x8, af[mi]), __builtin_bit_cast(f16x8, bf[ni]),
                    acc[mi][ni], 0, 0, 0);
    }

    // epilogue: D row = (l>>4)*4 + rr (m side), col = l&15 (n side)
#pragma unroll
    for (int ni = 0; ni < 4; ++ni) {
        int j = jb + wn * 64 + ni * 16 + lr;
        float bias = bih[j] + bhh[j];
#pragma unroll
        for (int mi = 0; mi < 4; ++mi) {
            long row = mbase + wm * 64 + mi * 16 + lk * 4;
#pragma unroll
            for (int rr = 0; rr < 4; ++rr)
                xp[(row + rr) * 512 + j] = (f16)(acc[mi][ni][rr] + bias);
        }
    }
}

// ---------------- Phase 2 (+fused phase 3): the recurrence ----------------
// grid = N (128) blocks, block = 512 threads (8 waves), one WG per batch row.
// W_hh f16 resident: 192 VGPRs/lane (k 0..47 of each lane's 64-k window) +
// 128 KB LDS (k 48..63), XOR-swizzled for conflict-free b128 reads.
__global__ __launch_bounds__(512) void rnn_seq(const f16* __restrict__ whh16,
                                               const f16* __restrict__ xp,
                                               const float* __restrict__ hin,
                                               float* __restrict__ out,
                                               const float* __restrict__ wout,
                                               const float* __restrict__ bout,
                                               int tc, int finalflag, int ytotal) {
    __shared__ uint4 WL[8192];      // 128 KB
    __shared__ f16 hb[2][512];      // h double buffer
    __shared__ f16 xb[2][512];      // xp double buffer (reused as f32 h in epilogue)

    int tid = threadIdx.x;
    int n = blockIdx.x;
    int i = tid & 7;                // k-group (8 groups x 64 k)
    int jg = tid >> 3;              // j-group (64 groups x 8 j)
    int sx = (i >> 2) & 1;          // bank swizzle bit
    int wlbase = (jg * 64 + i) * 2; // uint4 index

    // ---- load W_hh: regs (k local 0..47) + LDS (k local 48..63) ----
    uint4 wr[8][6];
    const f16* wbase = whh16 + (long)(jg * 8) * 512 + i * 64;
#pragma unroll
    for (int jj = 0; jj < 8; ++jj) {
        const uint4* p = (const uint4*)(wbase + jj * 512);
#pragma unroll
        for (int v = 0; v < 6; ++v) wr[jj][v] = p[v];
        uint4 c0 = p[6], c1 = p[7];
        WL[wlbase + jj * 16 + sx]       = c0;   // chunk (0 ^ sx)
        WL[wlbase + jj * 16 + (1 - sx)] = c1;   // chunk (1 ^ sx)
    }

    // ---- h0, xp[t=0] ----
    hb[0][tid] = (f16)hin[n * 512 + tid];
    const f16* xprow = xp + (long)n * tc * 512;
    if (tid < 64) *(uint4*)&xb[0][tid * 8] = *(const uint4*)(xprow + tid * 8);
    __syncthreads();

    int jfin = jg * 8 + (((i & 1) << 2) | (i & 2) | ((i >> 2) & 1)); // bit-reversed(i)
    int kb = i * 64;
    float lasth = 0.f;
    int cur = 0;

    for (int t = 0; t < tc; ++t) {
        uint4 pf;
        int dop = (tid < 64) && (t + 1 < tc);
        if (dop) pf = *(const uint4*)(xprow + (long)(t + 1) * 512 + tid * 8);  // issue early

        const uint4* hc = (const uint4*)&hb[cur][kb];
        float a[8];
#pragma unroll
        for (int jj = 0; jj < 8; ++jj) a[jj] = 0.f;

        uint4 h0 = hc[0], h1 = hc[1], h2 = hc[2];
#pragma unroll
        for (int jj = 0; jj < 8; ++jj) {
            a[jj] = dot4(wr[jj][0], h0, a[jj]);
            a[jj] = dot4(wr[jj][1], h1, a[jj]);
            a[jj] = dot4(wr[jj][2], h2, a[jj]);
        }
        h0 = hc[3]; h1 = hc[4]; h2 = hc[5];
#pragma unroll
        for (int jj = 0; jj < 8; ++jj) {
            a[jj] = dot4(wr[jj][3], h0, a[jj]);
            a[jj] = dot4(wr[jj][4], h1, a[jj]);
            a[jj] = dot4(wr[jj][5], h2, a[jj]);
        }
        h0 = hc[6]; h1 = hc[7];
#pragma unroll
        for (int jj = 0; jj < 8; ++jj) {
            uint4 wa = WL[wlbase + jj * 16 + sx];
            uint4 wb = WL[wlbase + jj * 16 + (1 - sx)];
            a[jj] = dot4(wa, h0, a[jj]);
            a[jj] = dot4(wb, h1, a[jj]);
        }

        // butterfly reduce over the 8 k-group lanes; each lane ends owning j = jfin
#pragma unroll
        for (int s = 0; s < 4; ++s) {
            float lo = a[s], hi = a[s + 4];
            float keep = (i & 1) ? hi : lo, send = (i & 1) ? lo : hi;
            a[s] = keep + __shfl_xor(send, 1);
        }
#pragma unroll
        for (int s = 0; s < 2; ++s) {
            float lo = a[s], hi = a[s + 2];
            float keep = (i & 2) ? hi : lo, send = (i & 2) ? lo : hi;
            a[s] = keep + __shfl_xor(send, 2);
        }
        {
            float lo = a[0], hi = a[1];
            float keep = (i & 4) ? hi : lo, send = (i & 4) ? lo : hi;
            a[0] = keep + __shfl_xor(send, 4);
        }

        float xv = (float)xb[cur][jfin];
        float pre = a[0] + xv;
        pre = fminf(fmaxf(pre, -20.f), 20.f);
        float e = __expf(2.f * pre);
        float hn = 1.f - 2.f / (e + 1.f);     // tanh
        lasth = hn;
        hb[cur ^ 1][jfin] = (f16)hn;
        if (dop) *(uint4*)&xb[cur ^ 1][tid * 8] = pf;   // write late
        __syncthreads();
        cur ^= 1;
    }

    out[ytotal + n * 512 + jfin] = lasth;    // h state (chunk handoff / final h)

    if (finalflag) {
        float* hf = (float*)&xb[0][0];       // 512 floats = 2 KB, reuse xb
        hf[jfin] = lasth;
        __syncthreads();
        int jy = tid;
        float acc = bout[jy];
        const float* wrp = wout + (long)jy * 512;
#pragma unroll 4
        for (int k = 0; k < 512; k += 8) {
            float4 w0 = *(const float4*)(wrp + k);
            float4 w1 = *(const float4*)(wrp + k + 4);
            float4 g0 = *(const float4*)(hf + k);
            float4 g1 = *(const float4*)(hf + k + 4);
            acc = fmaf(w0.x, g0.x, acc); acc = fmaf(w0.y, g0.y, acc);
            acc = fmaf(w0.z, g0.z, acc); acc = fmaf(w0.w, g0.w, acc);
            acc = fmaf(w1.x, g1.x, acc); acc = fmaf(w1.y, g1.y, acc);
            acc = fmaf(w1.z, g1.z, acc); acc = fmaf(w1.w, g1.w, acc);
        }
        out[n * 512 + jy] = acc;             // y
    }
}

extern "C" void kernel_launch(void* const* d_in, const int* in_sizes, int n_in,
                              void* d_out, int out_size, void* d_ws, size_t ws_size,
                              hipStream_t stream) {
    const float* x    = (const float*)d_in[0];
    const float* h0   = (const float*)d_in[1];
    const float* wih  = (const float*)d_in[2];
    const float* whh  = (const float*)d_in[3];
    const float* bih  = (const float*)d_in[4];
    const float* bhh  = (const float*)d_in[5];
    const float* wout = (const float*)d_in[6];
    const float* bout = (const float*)d_in[7];
    float* out = (float*)d_out;

    int N = in_sizes[1] / 512;                      // 128
    int L = (int)((long)in_sizes[0] / ((long)N * 256)); // 1024
    int ytotal = N * 512;

    char* ws = (char*)d_ws;
    f16* whh16 = (f16*)ws;                 // 524288 B
    f16* wih16 = (f16*)(ws + 524288);      // 262144 B
    f16* xp    = (f16*)(ws + 786432);
    long per_t = (long)N * 512 * 2;
    long cap = (ws_size > 786432) ? (long)(ws_size - 786432) : 0;
    long Tc = cap / per_t;
    if (Tc > L) Tc = L;
    if (Tc < 1) Tc = 1;

    cvt_w<<<384, 256, 0, stream>>>((const float4*)wih, (const float4*)whh,
                                   (f16x4*)wih16, (f16x4*)whh16);

    for (int t0 = 0; t0 < L;) {
        int tc = (int)((L - t0 < Tc) ? (L - t0) : Tc);
        gemm_xp<<<dim3(tc, 4), 256, 0, stream>>>(x, wih16, bih, bhh, xp, tc, t0, L);
        const float* hsrc = (t0 == 0) ? h0 : (const float*)(out + ytotal);
        int fin = (t0 + tc == L) ? 1 : 0;
        rnn_seq<<<N, 512, 0, stream>>>(whh16, xp, hsrc, out, wout, bout, tc, fin, ytotal);
        t0 += tc;
    }
}